// Round 13
// baseline (299.737 us; speedup 1.0000x reference)
//
#include <hip/hip_runtime.h>
#include <hip/hip_bf16.h>
#include <math.h>

namespace {
constexpr int kD = 256;      // embed dim
constexpr int kDOUT = 256;   // out dim
constexpr int kNQ = 65536;   // num query nodes
constexpr int kE = 262144;   // edges
constexpr float kAlpha = 0.2f;
constexpr float kEps = 1e-12f;
constexpr int kCap = 16;     // slots per query (P(deg>16) ~ 1e-6 per query)
constexpr int kOvfMax = 4096;
}

typedef short bf16x8 __attribute__((ext_vector_type(8)));
typedef float f32x4 __attribute__((ext_vector_type(4)));
typedef unsigned short u16x8 __attribute__((ext_vector_type(8)));

static __device__ __forceinline__ float bf2f(unsigned short u) {
  union { unsigned int i; float f; } v;
  v.i = ((unsigned int)u) << 16;
  return v.f;
}

// c[j] = sum_k a[k][j] * a2[k]   (a is (DOUT, 2D) row-major; j in [0, 512))
__global__ void compute_c_kernel(const float* __restrict__ a,
                                 const float* __restrict__ a2,
                                 float* __restrict__ c) {
  const int j = blockIdx.x * blockDim.x + threadIdx.x;  // 0..511
  float s = 0.f;
#pragma unroll 8
  for (int k = 0; k < kDOUT; ++k) s = fmaf(a[k * (2 * kD) + j], a2[k], s);
  c[j] = s;
}

// zero count[NQ] + ovf_n
__global__ void zero_kernel(int4* __restrict__ p, int* __restrict__ ovf_n) {
  p[blockIdx.x * 256 + threadIdx.x] = int4{0, 0, 0, 0};
  if (blockIdx.x == 0 && threadIdx.x == 0) *ovf_n = 0;
}

// trans (256x256 f32) -> bf16
__global__ void cvt_trans_kernel(const float* __restrict__ t, ushort* __restrict__ tb) {
  const int i = blockIdx.x * 256 + threadIdx.x;  // 4 elems each
  const float4 v = reinterpret_cast<const float4*>(t)[i];
  union { ushort4 u; __hip_bfloat16 h[4]; } p;
  p.h[0] = __float2bfloat16(v.x);
  p.h[1] = __float2bfloat16(v.y);
  p.h[2] = __float2bfloat16(v.z);
  p.h[3] = __float2bfloat16(v.w);
  reinterpret_cast<ushort4*>(tb)[i] = p.u;
}

// Sweep: 2 edges per wave (32 lanes each). Slot atomic HOISTED before row
// loads (latency hides under load+dot+reduce); rowsum atomic replaced by a
// plain ev_bins store; bf16(ev*key_row) written to the query's capacity bin.
__global__ __launch_bounds__(256) void sweep_kernel(
    const float* __restrict__ key_embed,
    const float* __restrict__ query_embed,
    const int* __restrict__ qlist,
    const float* __restrict__ c,
    int* __restrict__ count,
    float* __restrict__ ev_bins,
    int* __restrict__ ovf_n,
    int* __restrict__ ovf_q,
    float* __restrict__ ovf_ev,
    ushort* __restrict__ wovf,
    ushort* __restrict__ wkey) {
  const int wid = threadIdx.x >> 6;
  const int lane = threadIdx.x & 63;
  const int g = lane >> 5;        // edge sub-slot in wave
  const int l5 = lane & 31;       // lane within 32-group; floats [l5*8, +8)
  const int edge = blockIdx.x * 8 + wid * 2 + g;

  // (1) slot atomic first — overlaps the row loads below
  int q = 0, slot = 0;
  if (l5 == 0) {
    q = qlist[edge];
    slot = atomicAdd(&count[q], 1);
  }

  // (2) row loads: 4 independent 16B loads per lane
  const float4* kr = reinterpret_cast<const float4*>(key_embed) + (size_t)edge * 64 + l5 * 2;
  const float4* qr = reinterpret_cast<const float4*>(query_embed) + (size_t)edge * 64 + l5 * 2;
  const float4 k0 = kr[0], k1 = kr[1];
  const float4 q0 = qr[0], q1 = qr[1];
  const float4 c0 = reinterpret_cast<const float4*>(c)[l5 * 2];
  const float4 c1 = reinterpret_cast<const float4*>(c)[l5 * 2 + 1];
  const float4 d0 = reinterpret_cast<const float4*>(c)[64 + l5 * 2];
  const float4 d1 = reinterpret_cast<const float4*>(c)[64 + l5 * 2 + 1];

  // (3) dot -> 5-step 32-lane reduce -> exp
  float s = k0.x * c0.x + k0.y * c0.y + k0.z * c0.z + k0.w * c0.w
          + k1.x * c1.x + k1.y * c1.y + k1.z * c1.z + k1.w * c1.w
          + q0.x * d0.x + q0.y * d0.y + q0.z * d0.z + q0.w * d0.w
          + q1.x * d1.x + q1.y * d1.y + q1.z * d1.z + q1.w * d1.w;
#pragma unroll
  for (int off = 1; off < 32; off <<= 1) s += __shfl_xor(s, off, 64);

  const float p = (s > 0.f) ? s : kAlpha * s;   // leaky_relu
  const float ev = __expf(-p);

  q = __shfl(q, g * 32, 64);
  slot = __shfl(slot, g * 32, 64);

  union { u16x8 u; __hip_bfloat16 h[8]; } pk;
  pk.h[0] = __float2bfloat16(ev * k0.x);
  pk.h[1] = __float2bfloat16(ev * k0.y);
  pk.h[2] = __float2bfloat16(ev * k0.z);
  pk.h[3] = __float2bfloat16(ev * k0.w);
  pk.h[4] = __float2bfloat16(ev * k1.x);
  pk.h[5] = __float2bfloat16(ev * k1.y);
  pk.h[6] = __float2bfloat16(ev * k1.z);
  pk.h[7] = __float2bfloat16(ev * k1.w);

  if (slot < kCap) {
    *reinterpret_cast<u16x8*>(wkey + ((size_t)q * kCap + slot) * kD + l5 * 8) = pk.u;
    if (l5 == 0) ev_bins[q * kCap + slot] = ev;
  } else {                         // rare overflow
    int o = 0;
    if (l5 == 0) {
      o = atomicAdd(ovf_n, 1);
      if (o < kOvfMax) { ovf_q[o] = q; ovf_ev[o] = ev; }
    }
    o = __shfl(o, g * 32, 64);
    if (o < kOvfMax)
      *reinterpret_cast<u16x8*>(wovf + (size_t)o * kD + l5 * 8) = pk.u;
  }
}

// Fused gather + GEMM + elu. One wave per 16 queries (M-tile), N=256 in regs.
// Each lane sums its own 16B slices of its row's contiguous bin (8 loads in
// flight per slot, no cross-lane ops), normalizes into the MFMA A-fragment,
// then 8x16 MFMAs against L2-resident transb; writes out directly.
__global__ __launch_bounds__(256) void gather_gemm_kernel(
    const ushort* __restrict__ wkey,
    const float* __restrict__ ev_bins,
    const ushort* __restrict__ wovf,
    const int* __restrict__ ovf_q,
    const float* __restrict__ ovf_ev,
    const int* __restrict__ ovf_n,
    const int* __restrict__ count,
    const ushort* __restrict__ B,     // trans bf16 (DOUT x D row-major)
    float* __restrict__ out) {
  const int wid = threadIdx.x >> 6;
  const int lane = threadIdx.x & 63;
  const int q0 = (blockIdx.x * 4 + wid) * 16;
  const int m = lane & 15;
  const int kb = (lane >> 4) * 8;   // 0,8,16,24
  const int q = q0 + m;
  const int cnt = count[q];
  const int cm = min(cnt, kCap);

  float rs = 0.f;
  for (int s = 0; s < cm; ++s) rs += ev_bins[q * kCap + s];

  float a8[8][8] = {};   // [k-tile][j], all statically indexed
  const ushort* base = wkey + (size_t)q * kCap * kD + kb;
  for (int s = 0; s < cm; ++s) {
    u16x8 u[8];
#pragma unroll
    for (int t = 0; t < 8; ++t)
      u[t] = *reinterpret_cast<const u16x8*>(base + (size_t)s * kD + t * 32);
#pragma unroll
    for (int t = 0; t < 8; ++t)
#pragma unroll
      for (int j = 0; j < 8; ++j) a8[t][j] += bf2f((unsigned short)u[t][j]);
  }

  if (cnt > kCap) {      // rare overflow entries
    const int n = min(*ovf_n, kOvfMax);
    for (int i = 0; i < n; ++i) {
      if (ovf_q[i] == q) {
        rs += ovf_ev[i];
        const ushort* ob = wovf + (size_t)i * kD + kb;
#pragma unroll
        for (int t = 0; t < 8; ++t) {
          const u16x8 uo = *reinterpret_cast<const u16x8*>(ob + t * 32);
#pragma unroll
          for (int j = 0; j < 8; ++j) a8[t][j] += bf2f((unsigned short)uo[j]);
        }
      }
    }
  }

  const float inv = 1.0f / ((rs == 0.f) ? kEps : rs);
  bf16x8 af[8];
#pragma unroll
  for (int t = 0; t < 8; ++t) {
    union { u16x8 u; __hip_bfloat16 h[8]; bf16x8 b; } pk;
#pragma unroll
    for (int j = 0; j < 8; ++j) pk.h[j] = __float2bfloat16(a8[t][j] * inv);
    af[t] = pk.b;
  }

  f32x4 acc2[16] = {};
#pragma unroll
  for (int t = 0; t < 8; ++t) {
#pragma unroll
    for (int nt = 0; nt < 16; ++nt) {
      const bf16x8 bf =
          *reinterpret_cast<const bf16x8*>(&B[(size_t)(nt * 16 + m) * kD + t * 32 + kb]);
      acc2[nt] = __builtin_amdgcn_mfma_f32_16x16x32_bf16(af[t], bf, acc2[nt], 0, 0, 0);
    }
  }

#pragma unroll
  for (int nt = 0; nt < 16; ++nt) {
#pragma unroll
    for (int r = 0; r < 4; ++r) {
      const int row = q0 + (lane >> 4) * 4 + r;
      const float x = acc2[nt][r];
      out[(size_t)row * kDOUT + nt * 16 + m] = (x > 0.f) ? x : expm1f(x);
    }
  }
}

extern "C" void kernel_launch(void* const* d_in, const int* in_sizes, int n_in,
                              void* d_out, int out_size, void* d_ws, size_t ws_size,
                              hipStream_t stream) {
  // inputs: 0 key_list(int,E) [unused], 1 key_embed(f32,E*256), 2 query_list(int,E),
  //         3 query_embed(f32,E*256), 4 a(f32,256*512), 5 a_2(f32,256), 6 trans(f32,256*256)
  const float* key_embed = (const float*)d_in[1];
  const int* query_list = (const int*)d_in[2];
  const float* query_embed = (const float*)d_in[3];
  const float* a = (const float*)d_in[4];
  const float* a2 = (const float*)d_in[5];
  const float* trans = (const float*)d_in[6];
  float* out = (float*)d_out;

  // workspace layout (ushort units from base; wkey first for alignment):
  // wkey[NQ*16*256 us = 512MB] | transb[256*256 us] | wovf[kOvfMax*256 us]
  // | c[512 f] | count[NQ i] | ev_bins[NQ*16 f] | ovf_n[4 i] | ovf_q[kOvfMax i]
  // | ovf_ev[kOvfMax f]
  ushort* wkey = (ushort*)d_ws;
  ushort* transb = wkey + (size_t)kNQ * kCap * kD;
  ushort* wovf = transb + (size_t)kDOUT * kD;
  float* c = (float*)(wovf + (size_t)kOvfMax * kD);
  int* count = (int*)(c + 512);
  float* ev_bins = (float*)(count + kNQ);
  int* ovf_n = (int*)(ev_bins + (size_t)kNQ * kCap);
  int* ovf_q = ovf_n + 4;
  float* ovf_ev = (float*)(ovf_q + kOvfMax);

  zero_kernel<<<kNQ / 4 / 256, 256, 0, stream>>>((int4*)count, ovf_n);
  compute_c_kernel<<<2, 256, 0, stream>>>(a, a2, c);
  cvt_trans_kernel<<<kDOUT * kD / 4 / 256, 256, 0, stream>>>(trans, transb);
  sweep_kernel<<<kE / 8, 256, 0, stream>>>(key_embed, query_embed, query_list, c,
                                           count, ev_bins, ovf_n, ovf_q, ovf_ev,
                                           wovf, wkey);
  gather_gemm_kernel<<<kNQ / 64, 256, 0, stream>>>(wkey, ev_bins, wovf, ovf_q, ovf_ev,
                                                   ovf_n, count, transb, out);
}

// Round 14
// 262.032 us; speedup vs baseline: 1.1439x; 1.1439x over previous
//
#include <hip/hip_runtime.h>
#include <hip/hip_bf16.h>
#include <math.h>

namespace {
constexpr int kD = 256;      // embed dim
constexpr int kDOUT = 256;   // out dim
constexpr int kNQ = 65536;   // num query nodes
constexpr int kE = 262144;   // edges
constexpr float kAlpha = 0.2f;
constexpr float kEps = 1e-12f;
constexpr int kCap = 16;     // slots per query
constexpr int kOvfMax = 4096;
}

typedef short bf16x8 __attribute__((ext_vector_type(8)));
typedef float f32x4 __attribute__((ext_vector_type(4)));
typedef unsigned short u16x8 __attribute__((ext_vector_type(8)));

// c[j] = sum_k a[k][j] * a2[k]   (a is (DOUT, 2D) row-major; j in [0, 512))
__global__ void compute_c_kernel(const float* __restrict__ a,
                                 const float* __restrict__ a2,
                                 float* __restrict__ c) {
  const int j = blockIdx.x * blockDim.x + threadIdx.x;  // 0..511
  float s = 0.f;
#pragma unroll 8
  for (int k = 0; k < kDOUT; ++k) s = fmaf(a[k * (2 * kD) + j], a2[k], s);
  c[j] = s;
}

// zero count[NQ] + ovf_n
__global__ void zero_kernel(int4* __restrict__ p, int* __restrict__ ovf_n) {
  p[blockIdx.x * 256 + threadIdx.x] = int4{0, 0, 0, 0};
  if (blockIdx.x == 0 && threadIdx.x == 0) *ovf_n = 0;
}

// trans (256x256 f32) -> bf16
__global__ void cvt_trans_kernel(const float* __restrict__ t, ushort* __restrict__ tb) {
  const int i = blockIdx.x * 256 + threadIdx.x;  // 4 elems each
  const float4 v = reinterpret_cast<const float4*>(t)[i];
  union { ushort4 u; __hip_bfloat16 h[4]; } p;
  p.h[0] = __float2bfloat16(v.x);
  p.h[1] = __float2bfloat16(v.y);
  p.h[2] = __float2bfloat16(v.z);
  p.h[3] = __float2bfloat16(v.w);
  reinterpret_cast<ushort4*>(tb)[i] = p.u;
}

// Sweep (R3's edge_e shape, measured ~6.4 TB/s): one wave per edge, 64 lanes
// x float4 covers the two rows. ev = exp(-leaky(key.ck + query.cq)); lane 0
// claims a capacity-bin slot and posts ONE 8B store {edge_id, ev_bits}.
// No weighted-row materialization at all.
__global__ __launch_bounds__(256) void sweep_kernel(
    const float* __restrict__ key_embed,
    const float* __restrict__ query_embed,
    const int* __restrict__ qlist,
    const float* __restrict__ c,
    int* __restrict__ count,
    int2* __restrict__ bins,
    int* __restrict__ ovf_n,
    int* __restrict__ ovf_q,
    int* __restrict__ ovf_e,
    float* __restrict__ ovf_ev) {
  const int edge = (blockIdx.x << 2) + (threadIdx.x >> 6);
  const int lane = threadIdx.x & 63;

  const float4 k4 = reinterpret_cast<const float4*>(key_embed)[(size_t)edge * 64 + lane];
  const float4 q4 = reinterpret_cast<const float4*>(query_embed)[(size_t)edge * 64 + lane];
  const float4 ck = reinterpret_cast<const float4*>(c)[lane];
  const float4 cq = reinterpret_cast<const float4*>(c)[64 + lane];

  float s = k4.x * ck.x + k4.y * ck.y + k4.z * ck.z + k4.w * ck.w
          + q4.x * cq.x + q4.y * cq.y + q4.z * cq.z + q4.w * cq.w;
#pragma unroll
  for (int off = 32; off > 0; off >>= 1) s += __shfl_xor(s, off, 64);

  if (lane == 0) {
    const float p = (s > 0.f) ? s : kAlpha * s;   // leaky_relu
    const float ev = __expf(-p);
    const int q = qlist[edge];
    const int slot = atomicAdd(&count[q], 1);
    if (slot < kCap) {
      bins[q * kCap + slot] = make_int2(edge, __float_as_int(ev));
    } else {
      const int o = atomicAdd(ovf_n, 1);
      if (o < kOvfMax) { ovf_q[o] = q; ovf_e[o] = edge; ovf_ev[o] = ev; }
    }
  }
}

// Gather: 2 queries per wave (32 lanes x 8 floats each row). Reads bin
// {id, ev} pairs (contiguous 8B/lane), then the ORIGINAL f32 key rows
// (random 1KB granules, 4 rows in flight), scales by ev, accumulates f32,
// normalizes, writes bf16 accb row coalesced.
__global__ __launch_bounds__(256) void gather_kernel(
    const float* __restrict__ key_embed,
    const int2* __restrict__ bins,
    const int* __restrict__ count,
    const int* __restrict__ ovf_n,
    const int* __restrict__ ovf_q,
    const int* __restrict__ ovf_e,
    const float* __restrict__ ovf_ev,
    ushort* __restrict__ accb) {
  const int wid = threadIdx.x >> 6;
  const int lane = threadIdx.x & 63;
  const int g = lane >> 5;
  const int l5 = lane & 31;
  const int q = blockIdx.x * 8 + wid * 2 + g;

  const int cnt = count[q];
  const int cm = min(cnt, kCap);
  const int2 mybin = (l5 < cm) ? bins[q * kCap + l5] : make_int2(0, 0);

  float acc[8] = {};
  float rs = 0.f;

  for (int s = 0; s < cm; s += 4) {
    const int kc = min(4, cm - s);
    float4 r[4][2];
    float evs[4];
#pragma unroll
    for (int t = 0; t < 4; ++t) {
      if (t < kc) {
        const int eg = __shfl(mybin.x, (g << 5) + s + t, 64);
        evs[t] = __int_as_float(__shfl(mybin.y, (g << 5) + s + t, 64));
        const float4* row = reinterpret_cast<const float4*>(key_embed) + (size_t)eg * 64 + l5 * 2;
        r[t][0] = row[0];
        r[t][1] = row[1];
      }
    }
#pragma unroll
    for (int t = 0; t < 4; ++t) {
      if (t < kc) {
        acc[0] = fmaf(evs[t], r[t][0].x, acc[0]);
        acc[1] = fmaf(evs[t], r[t][0].y, acc[1]);
        acc[2] = fmaf(evs[t], r[t][0].z, acc[2]);
        acc[3] = fmaf(evs[t], r[t][0].w, acc[3]);
        acc[4] = fmaf(evs[t], r[t][1].x, acc[4]);
        acc[5] = fmaf(evs[t], r[t][1].y, acc[5]);
        acc[6] = fmaf(evs[t], r[t][1].z, acc[6]);
        acc[7] = fmaf(evs[t], r[t][1].w, acc[7]);
        rs += evs[t];
      }
    }
  }

  if (cnt > kCap) {   // rare: scan the tiny overflow list
    const int n = min(*ovf_n, kOvfMax);
    for (int i = 0; i < n; ++i) {
      if (ovf_q[i] == q) {
        const float ev = ovf_ev[i];
        const float4* row = reinterpret_cast<const float4*>(key_embed) +
                            (size_t)ovf_e[i] * 64 + l5 * 2;
        const float4 r0 = row[0], r1 = row[1];
        acc[0] = fmaf(ev, r0.x, acc[0]);
        acc[1] = fmaf(ev, r0.y, acc[1]);
        acc[2] = fmaf(ev, r0.z, acc[2]);
        acc[3] = fmaf(ev, r0.w, acc[3]);
        acc[4] = fmaf(ev, r1.x, acc[4]);
        acc[5] = fmaf(ev, r1.y, acc[5]);
        acc[6] = fmaf(ev, r1.z, acc[6]);
        acc[7] = fmaf(ev, r1.w, acc[7]);
        rs += ev;
      }
    }
  }

  const float inv = 1.0f / ((rs == 0.f) ? kEps : rs);
  union { u16x8 u; __hip_bfloat16 h[8]; } pk;
#pragma unroll
  for (int j = 0; j < 8; ++j) pk.h[j] = __float2bfloat16(acc[j] * inv);
  *reinterpret_cast<u16x8*>(accb + (size_t)q * kD + l5 * 8) = pk.u;
}

// out = elu(A @ B^T).  A: (NQ,256) bf16 row-major (pre-normalized), B = trans bf16.
// One wave per 16-row strip, full N=256 in registers (16 n-tiles of 16x16x32 MFMA).
__global__ __launch_bounds__(256) void out_gemm_mfma_kernel(
    const ushort* __restrict__ A,
    const ushort* __restrict__ B,
    float* __restrict__ out) {
  const int wid = threadIdx.x >> 6;
  const int lane = threadIdx.x & 63;
  const int row0 = (blockIdx.x * 4 + wid) * 16;
  const int m = lane & 15;
  const int kb = (lane >> 4) * 8;

  f32x4 acc[16] = {};

  for (int kt = 0; kt < kD; kt += 32) {
    const bf16x8 af = *reinterpret_cast<const bf16x8*>(&A[(size_t)(row0 + m) * kD + kt + kb]);
#pragma unroll
    for (int nt = 0; nt < 16; ++nt) {
      const bf16x8 bf = *reinterpret_cast<const bf16x8*>(&B[(size_t)(nt * 16 + m) * kD + kt + kb]);
      acc[nt] = __builtin_amdgcn_mfma_f32_16x16x32_bf16(af, bf, acc[nt], 0, 0, 0);
    }
  }

#pragma unroll
  for (int nt = 0; nt < 16; ++nt) {
#pragma unroll
    for (int r = 0; r < 4; ++r) {
      const int row = row0 + (lane >> 4) * 4 + r;
      const int col = nt * 16 + (lane & 15);
      const float x = acc[nt][r];
      out[(size_t)row * kDOUT + col] = (x > 0.f) ? x : expm1f(x);
    }
  }
}

extern "C" void kernel_launch(void* const* d_in, const int* in_sizes, int n_in,
                              void* d_out, int out_size, void* d_ws, size_t ws_size,
                              hipStream_t stream) {
  // inputs: 0 key_list(int,E) [unused], 1 key_embed(f32,E*256), 2 query_list(int,E),
  //         3 query_embed(f32,E*256), 4 a(f32,256*512), 5 a_2(f32,256), 6 trans(f32,256*256)
  const float* key_embed = (const float*)d_in[1];
  const int* query_list = (const int*)d_in[2];
  const float* query_embed = (const float*)d_in[3];
  const float* a = (const float*)d_in[4];
  const float* a2 = (const float*)d_in[5];
  const float* trans = (const float*)d_in[6];
  float* out = (float*)d_out;

  // workspace (4B units):
  // c[512] | count[NQ] | bins[NQ*16 int2] | accb[NQ*256 us] | transb[256*256 us]
  // | ovf_n[4] | ovf_q[kOvfMax] | ovf_e[kOvfMax] | ovf_ev[kOvfMax]
  float* ws = (float*)d_ws;
  float* c = ws;
  int* count = (int*)(c + 512);
  int2* bins = (int2*)(count + kNQ);
  ushort* accb = (ushort*)(bins + (size_t)kNQ * kCap);
  ushort* transb = accb + (size_t)kNQ * kD;
  int* ovf_n = (int*)(transb + (size_t)kDOUT * kD);
  int* ovf_q = ovf_n + 4;
  int* ovf_e = ovf_q + kOvfMax;
  float* ovf_ev = (float*)(ovf_e + kOvfMax);

  zero_kernel<<<kNQ / 4 / 256, 256, 0, stream>>>((int4*)count, ovf_n);
  compute_c_kernel<<<2, 256, 0, stream>>>(a, a2, c);
  cvt_trans_kernel<<<kDOUT * kD / 4 / 256, 256, 0, stream>>>(trans, transb);
  sweep_kernel<<<kE / 4, 256, 0, stream>>>(key_embed, query_embed, query_list, c,
                                           count, bins, ovf_n, ovf_q, ovf_e, ovf_ev);
  gather_kernel<<<kNQ / 8, 256, 0, stream>>>(key_embed, bins, count, ovf_n,
                                             ovf_q, ovf_e, ovf_ev, accb);
  out_gemm_mfma_kernel<<<kNQ / 64, 256, 0, stream>>>(accb, transb, out);
}

// Round 15
// 223.791 us; speedup vs baseline: 1.3394x; 1.1709x over previous
//
#include <hip/hip_runtime.h>
#include <hip/hip_bf16.h>
#include <math.h>

namespace {
constexpr int kD = 256;      // embed dim
constexpr int kDOUT = 256;   // out dim
constexpr int kNQ = 65536;   // num query nodes
constexpr int kE = 262144;   // edges
constexpr float kAlpha = 0.2f;
constexpr float kEps = 1e-12f;
constexpr int kCap = 16;     // slots per query
constexpr int kOvfMax = 4096;
}

typedef short bf16x8 __attribute__((ext_vector_type(8)));
typedef float f32x4 __attribute__((ext_vector_type(4)));
typedef unsigned short u16x8 __attribute__((ext_vector_type(8)));

// c[j] = sum_k a[k][j] * a2[k]   (a is (DOUT, 2D) row-major; j in [0, 512))
__global__ void compute_c_kernel(const float* __restrict__ a,
                                 const float* __restrict__ a2,
                                 float* __restrict__ c) {
  const int j = blockIdx.x * blockDim.x + threadIdx.x;  // 0..511
  float s = 0.f;
#pragma unroll 8
  for (int k = 0; k < kDOUT; ++k) s = fmaf(a[k * (2 * kD) + j], a2[k], s);
  c[j] = s;
}

// zero count[NQ] + ovf_n
__global__ void zero_kernel(int4* __restrict__ p, int* __restrict__ ovf_n) {
  p[blockIdx.x * 256 + threadIdx.x] = int4{0, 0, 0, 0};
  if (blockIdx.x == 0 && threadIdx.x == 0) *ovf_n = 0;
}

// trans (256x256 f32) -> bf16
__global__ void cvt_trans_kernel(const float* __restrict__ t, ushort* __restrict__ tb) {
  const int i = blockIdx.x * 256 + threadIdx.x;  // 4 elems each
  const float4 v = reinterpret_cast<const float4*>(t)[i];
  union { ushort4 u; __hip_bfloat16 h[4]; } p;
  p.h[0] = __float2bfloat16(v.x);
  p.h[1] = __float2bfloat16(v.y);
  p.h[2] = __float2bfloat16(v.z);
  p.h[3] = __float2bfloat16(v.w);
  reinterpret_cast<ushort4*>(tb)[i] = p.u;
}

// Sweep: reads ONLY query_embed. 4 edges per wave, 16 lanes per edge, each
// lane loads 4 float4 (quarter row). One shared compute sequence: dot +
// 4-step in-group reduce serves all 4 edges in parallel. Group-lane-0 claims
// a capacity-bin slot and posts an 8B {edge, qd} store.
__global__ __launch_bounds__(256) void qdot_bin_kernel(
    const float* __restrict__ query_embed,
    const int* __restrict__ qlist,
    const float* __restrict__ c,          // cq at c[256..512)
    int* __restrict__ count,
    int2* __restrict__ bins,
    int* __restrict__ ovf_n,
    int* __restrict__ ovf_q,
    int* __restrict__ ovf_e,
    float* __restrict__ ovf_qd) {
  const int wid = threadIdx.x >> 6;
  const int lane = threadIdx.x & 63;
  const int g = lane >> 4;      // edge slot in wave
  const int l4 = lane & 15;     // lane in 16-group; floats [l4*16, +16)
  const int edge = blockIdx.x * 16 + wid * 4 + g;

  int q = 0;
  if (l4 == 0) q = qlist[edge];   // issued early, in flight under row loads

  const float4* qr = reinterpret_cast<const float4*>(query_embed) + (size_t)edge * 64 + l4 * 4;
  const float4 r0 = qr[0], r1 = qr[1], r2 = qr[2], r3 = qr[3];
  const float4 c0 = reinterpret_cast<const float4*>(c)[64 + l4 * 4 + 0];
  const float4 c1 = reinterpret_cast<const float4*>(c)[64 + l4 * 4 + 1];
  const float4 c2 = reinterpret_cast<const float4*>(c)[64 + l4 * 4 + 2];
  const float4 c3 = reinterpret_cast<const float4*>(c)[64 + l4 * 4 + 3];

  float s = r0.x * c0.x + r0.y * c0.y + r0.z * c0.z + r0.w * c0.w
          + r1.x * c1.x + r1.y * c1.y + r1.z * c1.z + r1.w * c1.w
          + r2.x * c2.x + r2.y * c2.y + r2.z * c2.z + r2.w * c2.w
          + r3.x * c3.x + r3.y * c3.y + r3.z * c3.z + r3.w * c3.w;
#pragma unroll
  for (int off = 1; off < 16; off <<= 1) s += __shfl_xor(s, off, 64);

  if (l4 == 0) {
    const int slot = atomicAdd(&count[q], 1);
    if (slot < kCap) {
      bins[q * kCap + slot] = make_int2(edge, __float_as_int(s));
    } else {
      const int o = atomicAdd(ovf_n, 1);
      if (o < kOvfMax) { ovf_q[o] = q; ovf_e[o] = edge; ovf_qd[o] = s; }
    }
  }
}

// Gather: 2 queries per wave (32 lanes x 8 floats each). Reads bin
// {edge, qd} pairs, then the f32 key rows (random 1KB granules, 4 in
// flight). Computes kd = key.ck in-group (5-step reduce), ev =
// exp(-leaky(kd+qd)), accumulates ev*key + rowsum, normalizes, writes bf16.
__global__ __launch_bounds__(256) void gather_kernel(
    const float* __restrict__ key_embed,
    const float* __restrict__ c,          // ck at c[0..256)
    const int2* __restrict__ bins,
    const int* __restrict__ count,
    const int* __restrict__ ovf_n,
    const int* __restrict__ ovf_q,
    const int* __restrict__ ovf_e,
    const float* __restrict__ ovf_qd,
    ushort* __restrict__ accb) {
  const int wid = threadIdx.x >> 6;
  const int lane = threadIdx.x & 63;
  const int g = lane >> 5;
  const int l5 = lane & 31;
  const int q = blockIdx.x * 8 + wid * 2 + g;

  const int cnt = count[q];
  const int cm = min(cnt, kCap);
  const int2 mybin = (l5 < cm) ? bins[q * kCap + l5] : make_int2(0, 0);

  const float4 ck0 = reinterpret_cast<const float4*>(c)[l5 * 2 + 0];
  const float4 ck1 = reinterpret_cast<const float4*>(c)[l5 * 2 + 1];

  float acc[8] = {};
  float rs = 0.f;

  for (int s = 0; s < cm; s += 4) {
    const int kc = min(4, cm - s);
    float4 r[4][2];
    float qd[4];
#pragma unroll
    for (int t = 0; t < 4; ++t) {
      if (t < kc) {
        const int eg = __shfl(mybin.x, (g << 5) + s + t, 64);
        qd[t] = __int_as_float(__shfl(mybin.y, (g << 5) + s + t, 64));
        const float4* row = reinterpret_cast<const float4*>(key_embed) + (size_t)eg * 64 + l5 * 2;
        r[t][0] = row[0];
        r[t][1] = row[1];
      }
    }
#pragma unroll
    for (int t = 0; t < 4; ++t) {
      if (t < kc) {
        float kd = r[t][0].x * ck0.x + r[t][0].y * ck0.y + r[t][0].z * ck0.z + r[t][0].w * ck0.w
                 + r[t][1].x * ck1.x + r[t][1].y * ck1.y + r[t][1].z * ck1.z + r[t][1].w * ck1.w;
#pragma unroll
        for (int off = 1; off < 32; off <<= 1) kd += __shfl_xor(kd, off, 64);
        const float sv = kd + qd[t];
        const float p = (sv > 0.f) ? sv : kAlpha * sv;   // leaky_relu
        const float ev = __expf(-p);
        acc[0] = fmaf(ev, r[t][0].x, acc[0]);
        acc[1] = fmaf(ev, r[t][0].y, acc[1]);
        acc[2] = fmaf(ev, r[t][0].z, acc[2]);
        acc[3] = fmaf(ev, r[t][0].w, acc[3]);
        acc[4] = fmaf(ev, r[t][1].x, acc[4]);
        acc[5] = fmaf(ev, r[t][1].y, acc[5]);
        acc[6] = fmaf(ev, r[t][1].z, acc[6]);
        acc[7] = fmaf(ev, r[t][1].w, acc[7]);
        rs += ev;
      }
    }
  }

  if (cnt > kCap) {   // rare: scan the tiny overflow list
    const int n = min(*ovf_n, kOvfMax);
    for (int i = 0; i < n; ++i) {
      if (ovf_q[i] == q) {
        const float4* row = reinterpret_cast<const float4*>(key_embed) +
                            (size_t)ovf_e[i] * 64 + l5 * 2;
        const float4 r0 = row[0], r1 = row[1];
        float kd = r0.x * ck0.x + r0.y * ck0.y + r0.z * ck0.z + r0.w * ck0.w
                 + r1.x * ck1.x + r1.y * ck1.y + r1.z * ck1.z + r1.w * ck1.w;
#pragma unroll
        for (int off = 1; off < 32; off <<= 1) kd += __shfl_xor(kd, off, 64);
        const float sv = kd + ovf_qd[i];
        const float p = (sv > 0.f) ? sv : kAlpha * sv;
        const float ev = __expf(-p);
        acc[0] = fmaf(ev, r0.x, acc[0]);
        acc[1] = fmaf(ev, r0.y, acc[1]);
        acc[2] = fmaf(ev, r0.z, acc[2]);
        acc[3] = fmaf(ev, r0.w, acc[3]);
        acc[4] = fmaf(ev, r1.x, acc[4]);
        acc[5] = fmaf(ev, r1.y, acc[5]);
        acc[6] = fmaf(ev, r1.z, acc[6]);
        acc[7] = fmaf(ev, r1.w, acc[7]);
        rs += ev;
      }
    }
  }

  const float inv = 1.0f / ((rs == 0.f) ? kEps : rs);
  union { u16x8 u; __hip_bfloat16 h[8]; } pk;
#pragma unroll
  for (int j = 0; j < 8; ++j) pk.h[j] = __float2bfloat16(acc[j] * inv);
  *reinterpret_cast<u16x8*>(accb + (size_t)q * kD + l5 * 8) = pk.u;
}

// out = elu(A @ B^T).  A: (NQ,256) bf16 row-major (pre-normalized), B = trans bf16.
// One wave per 16-row strip, full N=256 in registers (16 n-tiles of 16x16x32 MFMA).
__global__ __launch_bounds__(256) void out_gemm_mfma_kernel(
    const ushort* __restrict__ A,
    const ushort* __restrict__ B,
    float* __restrict__ out) {
  const int wid = threadIdx.x >> 6;
  const int lane = threadIdx.x & 63;
  const int row0 = (blockIdx.x * 4 + wid) * 16;
  const int m = lane & 15;
  const int kb = (lane >> 4) * 8;

  f32x4 acc[16] = {};

  for (int kt = 0; kt < kD; kt += 32) {
    const bf16x8 af = *reinterpret_cast<const bf16x8*>(&A[(size_t)(row0 + m) * kD + kt + kb]);
#pragma unroll
    for (int nt = 0; nt < 16; ++nt) {
      const bf16x8 bf = *reinterpret_cast<const bf16x8*>(&B[(size_t)(nt * 16 + m) * kD + kt + kb]);
      acc[nt] = __builtin_amdgcn_mfma_f32_16x16x32_bf16(af, bf, acc[nt], 0, 0, 0);
    }
  }

#pragma unroll
  for (int nt = 0; nt < 16; ++nt) {
#pragma unroll
    for (int r = 0; r < 4; ++r) {
      const int row = row0 + (lane >> 4) * 4 + r;
      const int col = nt * 16 + (lane & 15);
      const float x = acc[nt][r];
      out[(size_t)row * kDOUT + col] = (x > 0.f) ? x : expm1f(x);
    }
  }
}

extern "C" void kernel_launch(void* const* d_in, const int* in_sizes, int n_in,
                              void* d_out, int out_size, void* d_ws, size_t ws_size,
                              hipStream_t stream) {
  // inputs: 0 key_list(int,E) [unused], 1 key_embed(f32,E*256), 2 query_list(int,E),
  //         3 query_embed(f32,E*256), 4 a(f32,256*512), 5 a_2(f32,256), 6 trans(f32,256*256)
  const float* key_embed = (const float*)d_in[1];
  const int* query_list = (const int*)d_in[2];
  const float* query_embed = (const float*)d_in[3];
  const float* a = (const float*)d_in[4];
  const float* a2 = (const float*)d_in[5];
  const float* trans = (const float*)d_in[6];
  float* out = (float*)d_out;

  // workspace (4B units):
  // c[512] | count[NQ] | bins[NQ*16 int2] | accb[NQ*256 us] | transb[256*256 us]
  // | ovf_n[4] | ovf_q[kOvfMax] | ovf_e[kOvfMax] | ovf_qd[kOvfMax]
  float* ws = (float*)d_ws;
  float* c = ws;
  int* count = (int*)(c + 512);
  int2* bins = (int2*)(count + kNQ);
  ushort* accb = (ushort*)(bins + (size_t)kNQ * kCap);
  ushort* transb = accb + (size_t)kNQ * kD;
  int* ovf_n = (int*)(transb + (size_t)kDOUT * kD);
  int* ovf_q = ovf_n + 4;
  int* ovf_e = ovf_q + kOvfMax;
  float* ovf_qd = (float*)(ovf_e + kOvfMax);

  zero_kernel<<<kNQ / 4 / 256, 256, 0, stream>>>((int4*)count, ovf_n);
  compute_c_kernel<<<2, 256, 0, stream>>>(a, a2, c);
  cvt_trans_kernel<<<kDOUT * kD / 4 / 256, 256, 0, stream>>>(trans, transb);
  qdot_bin_kernel<<<kE / 16, 256, 0, stream>>>(query_embed, query_list, c, count,
                                               bins, ovf_n, ovf_q, ovf_e, ovf_qd);
  gather_kernel<<<kNQ / 8, 256, 0, stream>>>(key_embed, c, bins, count, ovf_n,
                                             ovf_q, ovf_e, ovf_qd, accb);
  out_gemm_mfma_kernel<<<kNQ / 64, 256, 0, stream>>>(accb, transb, out);
}

// Round 16
// 213.703 us; speedup vs baseline: 1.4026x; 1.0472x over previous
//
#include <hip/hip_runtime.h>
#include <hip/hip_bf16.h>
#include <math.h>

namespace {
constexpr int kD = 256;      // embed dim
constexpr int kDOUT = 256;   // out dim
constexpr int kNQ = 65536;   // num query nodes
constexpr int kE = 262144;   // edges
constexpr float kAlpha = 0.2f;
constexpr float kEps = 1e-12f;
constexpr int kCap = 16;     // slots per query
constexpr int kOvfMax = 4096;
}

typedef short bf16x8 __attribute__((ext_vector_type(8)));
typedef float f32x4 __attribute__((ext_vector_type(4)));
typedef unsigned short u16x8 __attribute__((ext_vector_type(8)));

// c[j] = sum_k a[k][j] * a2[k]   (a is (DOUT, 2D) row-major; j in [0, 512))
__global__ void compute_c_kernel(const float* __restrict__ a,
                                 const float* __restrict__ a2,
                                 float* __restrict__ c) {
  const int j = blockIdx.x * blockDim.x + threadIdx.x;  // 0..511
  float s = 0.f;
#pragma unroll 8
  for (int k = 0; k < kDOUT; ++k) s = fmaf(a[k * (2 * kD) + j], a2[k], s);
  c[j] = s;
}

// zero count[NQ] + ovf_n
__global__ void zero_kernel(int4* __restrict__ p, int* __restrict__ ovf_n) {
  p[blockIdx.x * 256 + threadIdx.x] = int4{0, 0, 0, 0};
  if (blockIdx.x == 0 && threadIdx.x == 0) *ovf_n = 0;
}

// trans (256x256 f32) -> bf16
__global__ void cvt_trans_kernel(const float* __restrict__ t, ushort* __restrict__ tb) {
  const int i = blockIdx.x * 256 + threadIdx.x;  // 4 elems each
  const float4 v = reinterpret_cast<const float4*>(t)[i];
  union { ushort4 u; __hip_bfloat16 h[4]; } p;
  p.h[0] = __float2bfloat16(v.x);
  p.h[1] = __float2bfloat16(v.y);
  p.h[2] = __float2bfloat16(v.z);
  p.h[3] = __float2bfloat16(v.w);
  reinterpret_cast<ushort4*>(tb)[i] = p.u;
}

// Sweep: reads ONLY query_embed. 4 edges per wave, 16 lanes per edge, each
// lane loads 4 float4 (quarter row). Group-lane-0 claims a capacity-bin slot
// and posts an 8B {edge, qd} store.
__global__ __launch_bounds__(256) void qdot_bin_kernel(
    const float* __restrict__ query_embed,
    const int* __restrict__ qlist,
    const float* __restrict__ c,          // cq at c[256..512)
    int* __restrict__ count,
    int2* __restrict__ bins,
    int* __restrict__ ovf_n,
    int* __restrict__ ovf_q,
    int* __restrict__ ovf_e,
    float* __restrict__ ovf_qd) {
  const int wid = threadIdx.x >> 6;
  const int lane = threadIdx.x & 63;
  const int g = lane >> 4;      // edge slot in wave
  const int l4 = lane & 15;     // lane in 16-group; floats [l4*16, +16)
  const int edge = blockIdx.x * 16 + wid * 4 + g;

  int q = 0;
  if (l4 == 0) q = qlist[edge];   // issued early, in flight under row loads

  const float4* qr = reinterpret_cast<const float4*>(query_embed) + (size_t)edge * 64 + l4 * 4;
  const float4 r0 = qr[0], r1 = qr[1], r2 = qr[2], r3 = qr[3];
  const float4 c0 = reinterpret_cast<const float4*>(c)[64 + l4 * 4 + 0];
  const float4 c1 = reinterpret_cast<const float4*>(c)[64 + l4 * 4 + 1];
  const float4 c2 = reinterpret_cast<const float4*>(c)[64 + l4 * 4 + 2];
  const float4 c3 = reinterpret_cast<const float4*>(c)[64 + l4 * 4 + 3];

  float s = r0.x * c0.x + r0.y * c0.y + r0.z * c0.z + r0.w * c0.w
          + r1.x * c1.x + r1.y * c1.y + r1.z * c1.z + r1.w * c1.w
          + r2.x * c2.x + r2.y * c2.y + r2.z * c2.z + r2.w * c2.w
          + r3.x * c3.x + r3.y * c3.y + r3.z * c3.z + r3.w * c3.w;
#pragma unroll
  for (int off = 1; off < 16; off <<= 1) s += __shfl_xor(s, off, 64);

  if (l4 == 0) {
    const int slot = atomicAdd(&count[q], 1);
    if (slot < kCap) {
      bins[q * kCap + slot] = make_int2(edge, __float_as_int(s));
    } else {
      const int o = atomicAdd(ovf_n, 1);
      if (o < kOvfMax) { ovf_q[o] = q; ovf_e[o] = edge; ovf_qd[o] = s; }
    }
  }
}

// Fused gather + GEMM + elu. Block = 16 queries = one MFMA M-tile.
// Phase 1 (gather): 4 waves x 4 groups of 16 lanes; lane covers floats
// [l4*16,+16) (4 float4/row, 4 rows in flight = 16KB/wave). kd reduced in 4
// shfl steps; ev = exp(-leaky(kd+qd)); acc in f32; normalized bf16 row lands
// in padded LDS A-tile. Phase 2 (GEMM): wave w takes n-tiles 4w..4w+3, reads
// A from LDS (pad 8 -> 2-way conflict, free), B from L2-resident transb,
// writes out directly.
__global__ __launch_bounds__(256) void gather_gemm_kernel(
    const float* __restrict__ key_embed,
    const float* __restrict__ c,          // ck at c[0..256)
    const int2* __restrict__ bins,
    const int* __restrict__ count,
    const int* __restrict__ ovf_n,
    const int* __restrict__ ovf_q,
    const int* __restrict__ ovf_e,
    const float* __restrict__ ovf_qd,
    const ushort* __restrict__ B,         // trans bf16 (DOUT x D row-major)
    float* __restrict__ out) {
  __shared__ ushort A_lds[16][264];       // +8 pad: row stride 528B -> 2-way
  const int wid = threadIdx.x >> 6;
  const int lane = threadIdx.x & 63;
  const int g = lane >> 4;
  const int l4 = lane & 15;
  const int qloc = wid * 4 + g;           // 0..15
  const int q = blockIdx.x * 16 + qloc;

  const int cnt = count[q];
  const int cm = min(cnt, kCap);
  const int2 mybin = (l4 < cm) ? bins[q * kCap + l4] : make_int2(0, 0);

  const float4 ck0 = reinterpret_cast<const float4*>(c)[l4 * 4 + 0];
  const float4 ck1 = reinterpret_cast<const float4*>(c)[l4 * 4 + 1];
  const float4 ck2 = reinterpret_cast<const float4*>(c)[l4 * 4 + 2];
  const float4 ck3 = reinterpret_cast<const float4*>(c)[l4 * 4 + 3];

  float acc[16] = {};
  float rs = 0.f;

  for (int s = 0; s < cm; s += 4) {
    const int kc = min(4, cm - s);
    float4 r[4][4];
    float qd[4];
#pragma unroll
    for (int t = 0; t < 4; ++t) {
      if (t < kc) {
        const int eg = __shfl(mybin.x, (g << 4) + s + t, 64);
        qd[t] = __int_as_float(__shfl(mybin.y, (g << 4) + s + t, 64));
        const float4* row = reinterpret_cast<const float4*>(key_embed) + (size_t)eg * 64 + l4 * 4;
#pragma unroll
        for (int u = 0; u < 4; ++u) r[t][u] = row[u];
      }
    }
#pragma unroll
    for (int t = 0; t < 4; ++t) {
      if (t < kc) {
        float kd = r[t][0].x * ck0.x + r[t][0].y * ck0.y + r[t][0].z * ck0.z + r[t][0].w * ck0.w
                 + r[t][1].x * ck1.x + r[t][1].y * ck1.y + r[t][1].z * ck1.z + r[t][1].w * ck1.w
                 + r[t][2].x * ck2.x + r[t][2].y * ck2.y + r[t][2].z * ck2.z + r[t][2].w * ck2.w
                 + r[t][3].x * ck3.x + r[t][3].y * ck3.y + r[t][3].z * ck3.z + r[t][3].w * ck3.w;
#pragma unroll
        for (int off = 1; off < 16; off <<= 1) kd += __shfl_xor(kd, off, 64);
        const float sv = kd + qd[t];
        const float p = (sv > 0.f) ? sv : kAlpha * sv;   // leaky_relu
        const float ev = __expf(-p);
#pragma unroll
        for (int u = 0; u < 4; ++u) {
          acc[u * 4 + 0] = fmaf(ev, r[t][u].x, acc[u * 4 + 0]);
          acc[u * 4 + 1] = fmaf(ev, r[t][u].y, acc[u * 4 + 1]);
          acc[u * 4 + 2] = fmaf(ev, r[t][u].z, acc[u * 4 + 2]);
          acc[u * 4 + 3] = fmaf(ev, r[t][u].w, acc[u * 4 + 3]);
        }
        rs += ev;
      }
    }
  }

  if (cnt > kCap) {   // rare: scan the tiny overflow list
    const int n = min(*ovf_n, kOvfMax);
    for (int i = 0; i < n; ++i) {
      if (ovf_q[i] == q) {
        const float4* row = reinterpret_cast<const float4*>(key_embed) +
                            (size_t)ovf_e[i] * 64 + l4 * 4;
        float4 r4[4];
#pragma unroll
        for (int u = 0; u < 4; ++u) r4[u] = row[u];
        float kd = r4[0].x * ck0.x + r4[0].y * ck0.y + r4[0].z * ck0.z + r4[0].w * ck0.w
                 + r4[1].x * ck1.x + r4[1].y * ck1.y + r4[1].z * ck1.z + r4[1].w * ck1.w
                 + r4[2].x * ck2.x + r4[2].y * ck2.y + r4[2].z * ck2.z + r4[2].w * ck2.w
                 + r4[3].x * ck3.x + r4[3].y * ck3.y + r4[3].z * ck3.z + r4[3].w * ck3.w;
#pragma unroll
        for (int off = 1; off < 16; off <<= 1) kd += __shfl_xor(kd, off, 64);
        const float sv = kd + ovf_qd[i];
        const float p = (sv > 0.f) ? sv : kAlpha * sv;
        const float ev = __expf(-p);
#pragma unroll
        for (int u = 0; u < 4; ++u) {
          acc[u * 4 + 0] = fmaf(ev, r4[u].x, acc[u * 4 + 0]);
          acc[u * 4 + 1] = fmaf(ev, r4[u].y, acc[u * 4 + 1]);
          acc[u * 4 + 2] = fmaf(ev, r4[u].z, acc[u * 4 + 2]);
          acc[u * 4 + 3] = fmaf(ev, r4[u].w, acc[u * 4 + 3]);
        }
        rs += ev;
      }
    }
  }

  const float inv = 1.0f / ((rs == 0.f) ? kEps : rs);
  union { u16x8 u; __hip_bfloat16 h[8]; } p0, p1;
#pragma unroll
  for (int j = 0; j < 8; ++j) p0.h[j] = __float2bfloat16(acc[j] * inv);
#pragma unroll
  for (int j = 0; j < 8; ++j) p1.h[j] = __float2bfloat16(acc[8 + j] * inv);
  *reinterpret_cast<u16x8*>(&A_lds[qloc][l4 * 16]) = p0.u;
  *reinterpret_cast<u16x8*>(&A_lds[qloc][l4 * 16 + 8]) = p1.u;

  __syncthreads();

  // ---- phase 2: out[blk*16 .. +16) = elu(A @ B^T), wave w takes nt 4w..4w+3
  const int m = lane & 15;
  const int kb = (lane >> 4) * 8;
  f32x4 acc2[4] = {};

#pragma unroll
  for (int kt = 0; kt < kD; kt += 32) {
    const bf16x8 af = *reinterpret_cast<const bf16x8*>(&A_lds[m][kt + kb]);
#pragma unroll
    for (int nt = 0; nt < 4; ++nt) {
      const int ntg = wid * 4 + nt;
      const bf16x8 bf =
          *reinterpret_cast<const bf16x8*>(&B[(size_t)(ntg * 16 + m) * kD + kt + kb]);
      acc2[nt] = __builtin_amdgcn_mfma_f32_16x16x32_bf16(af, bf, acc2[nt], 0, 0, 0);
    }
  }

#pragma unroll
  for (int nt = 0; nt < 4; ++nt) {
    const int ntg = wid * 4 + nt;
#pragma unroll
    for (int r = 0; r < 4; ++r) {
      const int row = blockIdx.x * 16 + (lane >> 4) * 4 + r;
      const float x = acc2[nt][r];
      out[(size_t)row * kDOUT + ntg * 16 + m] = (x > 0.f) ? x : expm1f(x);
    }
  }
}

extern "C" void kernel_launch(void* const* d_in, const int* in_sizes, int n_in,
                              void* d_out, int out_size, void* d_ws, size_t ws_size,
                              hipStream_t stream) {
  // inputs: 0 key_list(int,E) [unused], 1 key_embed(f32,E*256), 2 query_list(int,E),
  //         3 query_embed(f32,E*256), 4 a(f32,256*512), 5 a_2(f32,256), 6 trans(f32,256*256)
  const float* key_embed = (const float*)d_in[1];
  const int* query_list = (const int*)d_in[2];
  const float* query_embed = (const float*)d_in[3];
  const float* a = (const float*)d_in[4];
  const float* a2 = (const float*)d_in[5];
  const float* trans = (const float*)d_in[6];
  float* out = (float*)d_out;

  // workspace (4B units):
  // c[512] | count[NQ] | bins[NQ*16 int2] | transb[256*256 us]
  // | ovf_n[4] | ovf_q[kOvfMax] | ovf_e[kOvfMax] | ovf_qd[kOvfMax]
  float* ws = (float*)d_ws;
  float* c = ws;
  int* count = (int*)(c + 512);
  int2* bins = (int2*)(count + kNQ);
  ushort* transb = (ushort*)(bins + (size_t)kNQ * kCap);
  int* ovf_n = (int*)(transb + (size_t)kDOUT * kD);
  int* ovf_q = ovf_n + 4;
  int* ovf_e = ovf_q + kOvfMax;
  float* ovf_qd = (float*)(ovf_e + kOvfMax);

  zero_kernel<<<kNQ / 4 / 256, 256, 0, stream>>>((int4*)count, ovf_n);
  compute_c_kernel<<<2, 256, 0, stream>>>(a, a2, c);
  cvt_trans_kernel<<<kDOUT * kD / 4 / 256, 256, 0, stream>>>(trans, transb);
  qdot_bin_kernel<<<kE / 16, 256, 0, stream>>>(query_embed, query_list, c, count,
                                               bins, ovf_n, ovf_q, ovf_e, ovf_qd);
  gather_gemm_kernel<<<kNQ / 16, 256, 0, stream>>>(key_embed, c, bins, count, ovf_n,
                                                   ovf_q, ovf_e, ovf_qd, transb, out);
}

// Round 17
// 199.594 us; speedup vs baseline: 1.5017x; 1.0707x over previous
//
#include <hip/hip_runtime.h>
#include <hip/hip_bf16.h>
#include <math.h>

namespace {
constexpr int kD = 256;      // embed dim
constexpr int kDOUT = 256;   // out dim
constexpr int kNQ = 65536;   // num query nodes
constexpr int kE = 262144;   // edges
constexpr float kAlpha = 0.2f;
constexpr float kEps = 1e-12f;
constexpr int kCap = 16;     // slots per query
constexpr int kOvfMax = 4096;
}

typedef short bf16x8 __attribute__((ext_vector_type(8)));
typedef float f32x4 __attribute__((ext_vector_type(4)));
typedef unsigned short u16x8 __attribute__((ext_vector_type(8)));

// Fused prep: blocks 0..63 zero count (+ovf_n); 64..65 compute c; 66..129 cvt trans.
__global__ __launch_bounds__(256) void prep_kernel(
    const float* __restrict__ a,
    const float* __restrict__ a2,
    const float* __restrict__ trans,
    int4* __restrict__ count4,
    int* __restrict__ ovf_n,
    float* __restrict__ c,
    ushort* __restrict__ tb) {
  const int b = blockIdx.x;
  const int tid = threadIdx.x;
  if (b < 64) {
    count4[b * 256 + tid] = int4{0, 0, 0, 0};
    if (b == 0 && tid == 0) *ovf_n = 0;
  } else if (b < 66) {
    const int j = (b - 64) * 256 + tid;  // 0..511
    float s = 0.f;
#pragma unroll 8
    for (int k = 0; k < kDOUT; ++k) s = fmaf(a[k * (2 * kD) + j], a2[k], s);
    c[j] = s;
  } else {
    const int i = (b - 66) * 256 + tid;  // 0..16383, 4 elems each
    const float4 v = reinterpret_cast<const float4*>(trans)[i];
    union { ushort4 u; __hip_bfloat16 h[4]; } p;
    p.h[0] = __float2bfloat16(v.x);
    p.h[1] = __float2bfloat16(v.y);
    p.h[2] = __float2bfloat16(v.z);
    p.h[3] = __float2bfloat16(v.w);
    reinterpret_cast<ushort4*>(tb)[i] = p.u;
  }
}

// Sweep: reads ONLY query_embed. 4 edges per wave, 16 lanes per edge, each
// lane loads 4 float4 (quarter row). Group-lane-0 claims a capacity-bin slot
// and posts an 8B {edge, qd} store.
__global__ __launch_bounds__(256) void qdot_bin_kernel(
    const float* __restrict__ query_embed,
    const int* __restrict__ qlist,
    const float* __restrict__ c,          // cq at c[256..512)
    int* __restrict__ count,
    int2* __restrict__ bins,
    int* __restrict__ ovf_n,
    int* __restrict__ ovf_q,
    int* __restrict__ ovf_e,
    float* __restrict__ ovf_qd) {
  const int wid = threadIdx.x >> 6;
  const int lane = threadIdx.x & 63;
  const int g = lane >> 4;      // edge slot in wave
  const int l4 = lane & 15;     // lane in 16-group; floats [l4*16, +16)
  const int edge = blockIdx.x * 16 + wid * 4 + g;

  int q = 0;
  if (l4 == 0) q = qlist[edge];   // issued early, in flight under row loads

  const float4* qr = reinterpret_cast<const float4*>(query_embed) + (size_t)edge * 64 + l4 * 4;
  const float4 r0 = qr[0], r1 = qr[1], r2 = qr[2], r3 = qr[3];
  const float4 c0 = reinterpret_cast<const float4*>(c)[64 + l4 * 4 + 0];
  const float4 c1 = reinterpret_cast<const float4*>(c)[64 + l4 * 4 + 1];
  const float4 c2 = reinterpret_cast<const float4*>(c)[64 + l4 * 4 + 2];
  const float4 c3 = reinterpret_cast<const float4*>(c)[64 + l4 * 4 + 3];

  float s = r0.x * c0.x + r0.y * c0.y + r0.z * c0.z + r0.w * c0.w
          + r1.x * c1.x + r1.y * c1.y + r1.z * c1.z + r1.w * c1.w
          + r2.x * c2.x + r2.y * c2.y + r2.z * c2.z + r2.w * c2.w
          + r3.x * c3.x + r3.y * c3.y + r3.z * c3.z + r3.w * c3.w;
#pragma unroll
  for (int off = 1; off < 16; off <<= 1) s += __shfl_xor(s, off, 64);

  if (l4 == 0) {
    const int slot = atomicAdd(&count[q], 1);
    if (slot < kCap) {
      bins[q * kCap + slot] = make_int2(edge, __float_as_int(s));
    } else {
      const int o = atomicAdd(ovf_n, 1);
      if (o < kOvfMax) { ovf_q[o] = q; ovf_e[o] = edge; ovf_qd[o] = s; }
    }
  }
}

// Fused gather + GEMM + elu. Block = 32 queries = two MFMA M-tiles.
// Phase 1: 16 groups of 16 lanes; each group gathers 2 queries (g, g+16)
// sequentially into the padded LDS A-tile (4 rows of 4xfloat4 in flight).
// Phase 2: wave w takes n-tiles 4w..4w+3; each B fragment is loaded ONCE and
// feeds TWO MFMAs (both M-tiles) -> half the B L2 traffic of 16-query blocks.
__global__ __launch_bounds__(256) void gather_gemm_kernel(
    const float* __restrict__ key_embed,
    const float* __restrict__ c,          // ck at c[0..256)
    const int2* __restrict__ bins,
    const int* __restrict__ count,
    const int* __restrict__ ovf_n,
    const int* __restrict__ ovf_q,
    const int* __restrict__ ovf_e,
    const float* __restrict__ ovf_qd,
    const ushort* __restrict__ B,         // trans bf16 (DOUT x D row-major)
    float* __restrict__ out) {
  __shared__ ushort A_lds[32][264];       // +8 pad
  const int wid = threadIdx.x >> 6;
  const int lane = threadIdx.x & 63;
  const int g = lane >> 4;
  const int l4 = lane & 15;
  const int group = wid * 4 + g;          // 0..15

  const float4 ck0 = reinterpret_cast<const float4*>(c)[l4 * 4 + 0];
  const float4 ck1 = reinterpret_cast<const float4*>(c)[l4 * 4 + 1];
  const float4 ck2 = reinterpret_cast<const float4*>(c)[l4 * 4 + 2];
  const float4 ck3 = reinterpret_cast<const float4*>(c)[l4 * 4 + 3];

  for (int half = 0; half < 2; ++half) {
    const int qloc = half * 16 + group;
    const int q = blockIdx.x * 32 + qloc;
    const int cnt = count[q];
    const int cm = min(cnt, kCap);
    const int2 mybin = (l4 < cm) ? bins[q * kCap + l4] : make_int2(0, 0);

    float acc[16] = {};
    float rs = 0.f;

    for (int s = 0; s < cm; s += 4) {
      const int kc = min(4, cm - s);
      float4 r[4][4];
      float qd[4];
#pragma unroll
      for (int t = 0; t < 4; ++t) {
        if (t < kc) {
          const int eg = __shfl(mybin.x, (g << 4) + s + t, 64);
          qd[t] = __int_as_float(__shfl(mybin.y, (g << 4) + s + t, 64));
          const float4* row = reinterpret_cast<const float4*>(key_embed) + (size_t)eg * 64 + l4 * 4;
#pragma unroll
          for (int u = 0; u < 4; ++u) r[t][u] = row[u];
        }
      }
#pragma unroll
      for (int t = 0; t < 4; ++t) {
        if (t < kc) {
          float kd = r[t][0].x * ck0.x + r[t][0].y * ck0.y + r[t][0].z * ck0.z + r[t][0].w * ck0.w
                   + r[t][1].x * ck1.x + r[t][1].y * ck1.y + r[t][1].z * ck1.z + r[t][1].w * ck1.w
                   + r[t][2].x * ck2.x + r[t][2].y * ck2.y + r[t][2].z * ck2.z + r[t][2].w * ck2.w
                   + r[t][3].x * ck3.x + r[t][3].y * ck3.y + r[t][3].z * ck3.z + r[t][3].w * ck3.w;
#pragma unroll
          for (int off = 1; off < 16; off <<= 1) kd += __shfl_xor(kd, off, 64);
          const float sv = kd + qd[t];
          const float p = (sv > 0.f) ? sv : kAlpha * sv;   // leaky_relu
          const float ev = __expf(-p);
#pragma unroll
          for (int u = 0; u < 4; ++u) {
            acc[u * 4 + 0] = fmaf(ev, r[t][u].x, acc[u * 4 + 0]);
            acc[u * 4 + 1] = fmaf(ev, r[t][u].y, acc[u * 4 + 1]);
            acc[u * 4 + 2] = fmaf(ev, r[t][u].z, acc[u * 4 + 2]);
            acc[u * 4 + 3] = fmaf(ev, r[t][u].w, acc[u * 4 + 3]);
          }
          rs += ev;
        }
      }
    }

    if (cnt > kCap) {   // rare: scan the tiny overflow list
      const int n = min(*ovf_n, kOvfMax);
      for (int i = 0; i < n; ++i) {
        if (ovf_q[i] == q) {
          const float4* row = reinterpret_cast<const float4*>(key_embed) +
                              (size_t)ovf_e[i] * 64 + l4 * 4;
          float4 r4[4];
#pragma unroll
          for (int u = 0; u < 4; ++u) r4[u] = row[u];
          float kd = r4[0].x * ck0.x + r4[0].y * ck0.y + r4[0].z * ck0.z + r4[0].w * ck0.w
                   + r4[1].x * ck1.x + r4[1].y * ck1.y + r4[1].z * ck1.z + r4[1].w * ck1.w
                   + r4[2].x * ck2.x + r4[2].y * ck2.y + r4[2].z * ck2.z + r4[2].w * ck2.w
                   + r4[3].x * ck3.x + r4[3].y * ck3.y + r4[3].z * ck3.z + r4[3].w * ck3.w;
#pragma unroll
          for (int off = 1; off < 16; off <<= 1) kd += __shfl_xor(kd, off, 64);
          const float sv = kd + ovf_qd[i];
          const float p = (sv > 0.f) ? sv : kAlpha * sv;
          const float ev = __expf(-p);
#pragma unroll
          for (int u = 0; u < 4; ++u) {
            acc[u * 4 + 0] = fmaf(ev, r4[u].x, acc[u * 4 + 0]);
            acc[u * 4 + 1] = fmaf(ev, r4[u].y, acc[u * 4 + 1]);
            acc[u * 4 + 2] = fmaf(ev, r4[u].z, acc[u * 4 + 2]);
            acc[u * 4 + 3] = fmaf(ev, r4[u].w, acc[u * 4 + 3]);
          }
          rs += ev;
        }
      }
    }

    const float inv = 1.0f / ((rs == 0.f) ? kEps : rs);
    union { u16x8 u; __hip_bfloat16 h[8]; } p0, p1;
#pragma unroll
    for (int j = 0; j < 8; ++j) p0.h[j] = __float2bfloat16(acc[j] * inv);
#pragma unroll
    for (int j = 0; j < 8; ++j) p1.h[j] = __float2bfloat16(acc[8 + j] * inv);
    *reinterpret_cast<u16x8*>(&A_lds[qloc][l4 * 16]) = p0.u;
    *reinterpret_cast<u16x8*>(&A_lds[qloc][l4 * 16 + 8]) = p1.u;
  }

  __syncthreads();

  // ---- phase 2: two M-tiles; each B fragment feeds both
  const int m = lane & 15;
  const int kb = (lane >> 4) * 8;
  f32x4 accA[4] = {};
  f32x4 accB[4] = {};

#pragma unroll
  for (int kt = 0; kt < kD; kt += 32) {
    const bf16x8 af0 = *reinterpret_cast<const bf16x8*>(&A_lds[m][kt + kb]);
    const bf16x8 af1 = *reinterpret_cast<const bf16x8*>(&A_lds[16 + m][kt + kb]);
#pragma unroll
    for (int nt = 0; nt < 4; ++nt) {
      const int ntg = wid * 4 + nt;
      const bf16x8 bf =
          *reinterpret_cast<const bf16x8*>(&B[(size_t)(ntg * 16 + m) * kD + kt + kb]);
      accA[nt] = __builtin_amdgcn_mfma_f32_16x16x32_bf16(af0, bf, accA[nt], 0, 0, 0);
      accB[nt] = __builtin_amdgcn_mfma_f32_16x16x32_bf16(af1, bf, accB[nt], 0, 0, 0);
    }
  }

#pragma unroll
  for (int nt = 0; nt < 4; ++nt) {
    const int ntg = wid * 4 + nt;
#pragma unroll
    for (int r = 0; r < 4; ++r) {
      const int rbase = blockIdx.x * 32 + (lane >> 4) * 4 + r;
      const float xa = accA[nt][r];
      out[(size_t)rbase * kDOUT + ntg * 16 + m] = (xa > 0.f) ? xa : expm1f(xa);
      const float xb = accB[nt][r];
      out[(size_t)(rbase + 16) * kDOUT + ntg * 16 + m] = (xb > 0.f) ? xb : expm1f(xb);
    }
  }
}

extern "C" void kernel_launch(void* const* d_in, const int* in_sizes, int n_in,
                              void* d_out, int out_size, void* d_ws, size_t ws_size,
                              hipStream_t stream) {
  // inputs: 0 key_list(int,E) [unused], 1 key_embed(f32,E*256), 2 query_list(int,E),
  //         3 query_embed(f32,E*256), 4 a(f32,256*512), 5 a_2(f32,256), 6 trans(f32,256*256)
  const float* key_embed = (const float*)d_in[1];
  const int* query_list = (const int*)d_in[2];
  const float* query_embed = (const float*)d_in[3];
  const float* a = (const float*)d_in[4];
  const float* a2 = (const float*)d_in[5];
  const float* trans = (const float*)d_in[6];
  float* out = (float*)d_out;

  // workspace (4B units):
  // c[512] | count[NQ] | bins[NQ*16 int2] | transb[256*256 us]
  // | ovf_n[4] | ovf_q[kOvfMax] | ovf_e[kOvfMax] | ovf_qd[kOvfMax]
  float* ws = (float*)d_ws;
  float* c = ws;
  int* count = (int*)(c + 512);
  int2* bins = (int2*)(count + kNQ);
  ushort* transb = (ushort*)(bins + (size_t)kNQ * kCap);
  int* ovf_n = (int*)(transb + (size_t)kDOUT * kD);
  int* ovf_q = ovf_n + 4;
  int* ovf_e = ovf_q + kOvfMax;
  float* ovf_qd = (float*)(ovf_e + kOvfMax);

  prep_kernel<<<130, 256, 0, stream>>>(a, a2, trans, (int4*)count, ovf_n, c, transb);
  qdot_bin_kernel<<<kE / 16, 256, 0, stream>>>(query_embed, query_list, c, count,
                                               bins, ovf_n, ovf_q, ovf_e, ovf_qd);
  gather_gemm_kernel<<<kNQ / 32, 256, 0, stream>>>(key_embed, c, bins, count, ovf_n,
                                                   ovf_q, ovf_e, ovf_qd, transb, out);
}

// Round 18
// 188.809 us; speedup vs baseline: 1.5875x; 1.0571x over previous
//
#include <hip/hip_runtime.h>
#include <hip/hip_bf16.h>
#include <math.h>

namespace {
constexpr int kD = 256;      // embed dim
constexpr int kDOUT = 256;   // out dim
constexpr int kNQ = 65536;   // num query nodes
constexpr int kE = 262144;   // edges
constexpr float kAlpha = 0.2f;
constexpr float kEps = 1e-12f;
constexpr int kCap = 16;     // slots per query
constexpr int kOvfMax = 4096;
}

typedef short bf16x8 __attribute__((ext_vector_type(8)));
typedef float f32x4 __attribute__((ext_vector_type(4)));
typedef unsigned short u16x8 __attribute__((ext_vector_type(8)));

// Fused prep: blocks 0..63 zero count (+ovf_n); 64..65 compute c; 66..129 cvt trans.
__global__ __launch_bounds__(256) void prep_kernel(
    const float* __restrict__ a,
    const float* __restrict__ a2,
    const float* __restrict__ trans,
    int4* __restrict__ count4,
    int* __restrict__ ovf_n,
    float* __restrict__ c,
    ushort* __restrict__ tb) {
  const int b = blockIdx.x;
  const int tid = threadIdx.x;
  if (b < 64) {
    count4[b * 256 + tid] = int4{0, 0, 0, 0};
    if (b == 0 && tid == 0) *ovf_n = 0;
  } else if (b < 66) {
    const int j = (b - 64) * 256 + tid;  // 0..511
    float s = 0.f;
#pragma unroll 8
    for (int k = 0; k < kDOUT; ++k) s = fmaf(a[k * (2 * kD) + j], a2[k], s);
    c[j] = s;
  } else {
    const int i = (b - 66) * 256 + tid;  // 0..16383, 4 elems each
    const float4 v = reinterpret_cast<const float4*>(trans)[i];
    union { ushort4 u; __hip_bfloat16 h[4]; } p;
    p.h[0] = __float2bfloat16(v.x);
    p.h[1] = __float2bfloat16(v.y);
    p.h[2] = __float2bfloat16(v.z);
    p.h[3] = __float2bfloat16(v.w);
    reinterpret_cast<ushort4*>(tb)[i] = p.u;
  }
}

// Sweep: reads ONLY query_embed. 4 edges per wave, 16 lanes per edge, each
// lane loads 4 float4 (quarter row). Group-lane-0 claims a capacity-bin slot
// and posts an 8B {edge, qd} store.
__global__ __launch_bounds__(256) void qdot_bin_kernel(
    const float* __restrict__ query_embed,
    const int* __restrict__ qlist,
    const float* __restrict__ c,          // cq at c[256..512)
    int* __restrict__ count,
    int2* __restrict__ bins,
    int* __restrict__ ovf_n,
    int* __restrict__ ovf_q,
    int* __restrict__ ovf_e,
    float* __restrict__ ovf_qd) {
  const int wid = threadIdx.x >> 6;
  const int lane = threadIdx.x & 63;
  const int g = lane >> 4;      // edge slot in wave
  const int l4 = lane & 15;     // lane in 16-group; floats [l4*16, +16)
  const int edge = blockIdx.x * 16 + wid * 4 + g;

  int q = 0;
  if (l4 == 0) q = qlist[edge];   // issued early, in flight under row loads

  const float4* qr = reinterpret_cast<const float4*>(query_embed) + (size_t)edge * 64 + l4 * 4;
  const float4 r0 = qr[0], r1 = qr[1], r2 = qr[2], r3 = qr[3];
  const float4 c0 = reinterpret_cast<const float4*>(c)[64 + l4 * 4 + 0];
  const float4 c1 = reinterpret_cast<const float4*>(c)[64 + l4 * 4 + 1];
  const float4 c2 = reinterpret_cast<const float4*>(c)[64 + l4 * 4 + 2];
  const float4 c3 = reinterpret_cast<const float4*>(c)[64 + l4 * 4 + 3];

  float s = r0.x * c0.x + r0.y * c0.y + r0.z * c0.z + r0.w * c0.w
          + r1.x * c1.x + r1.y * c1.y + r1.z * c1.z + r1.w * c1.w
          + r2.x * c2.x + r2.y * c2.y + r2.z * c2.z + r2.w * c2.w
          + r3.x * c3.x + r3.y * c3.y + r3.z * c3.z + r3.w * c3.w;
#pragma unroll
  for (int off = 1; off < 16; off <<= 1) s += __shfl_xor(s, off, 64);

  if (l4 == 0) {
    const int slot = atomicAdd(&count[q], 1);
    if (slot < kCap) {
      bins[q * kCap + slot] = make_int2(edge, __float_as_int(s));
    } else {
      const int o = atomicAdd(ovf_n, 1);
      if (o < kOvfMax) { ovf_q[o] = q; ovf_e[o] = edge; ovf_qd[o] = s; }
    }
  }
}

// Fused gather + GEMM + elu. Block = 32 queries = two MFMA M-tiles.
// Phase 1: each WAVE owns 8 queries. Counts + all 8 bin vectors preloaded
// (independent). Then a branchless static 8-query x 8-slot loop of
// WHOLE-WAVE 1KB row loads (one instruction = one granule; clamped slot ->
// duplicate loads are L2-served, ev masked 0), 6-shfl reduce, f32 acc.
// Rare: dynamic slots 8..16, overflow list for deg>16. Normalized bf16 rows
// land in padded LDS. Phase 2: wave w takes n-tiles 4w..4w+3; each B
// fragment feeds both M-tiles.
__global__ __launch_bounds__(256) void gather_gemm_kernel(
    const float* __restrict__ key_embed,
    const float* __restrict__ c,          // ck at c[0..256)
    const int2* __restrict__ bins,
    const int* __restrict__ count,
    const int* __restrict__ ovf_n,
    const int* __restrict__ ovf_q,
    const int* __restrict__ ovf_e,
    const float* __restrict__ ovf_qd,
    const ushort* __restrict__ B,         // trans bf16 (DOUT x D row-major)
    float* __restrict__ out) {
  __shared__ ushort A_lds[32][264];       // +8 pad
  const int wid = threadIdx.x >> 6;
  const int lane = threadIdx.x & 63;
  const int qbase = blockIdx.x * 32 + wid * 8;   // wave owns 8 queries

  // lane covers floats [lane*4, +4) of every row
  const float4 ck = reinterpret_cast<const float4*>(c)[lane];

  const int cnt_l = (lane < 8) ? count[qbase + lane] : 0;
  int2 b[8];
  int cnts[8];
#pragma unroll
  for (int i = 0; i < 8; ++i) {
    cnts[i] = __shfl(cnt_l, i, 64);
    const int cmi = min(cnts[i], kCap);
    b[i] = (lane < cmi) ? bins[(size_t)(qbase + i) * kCap + lane] : make_int2(0, 0);
  }

#pragma unroll
  for (int i = 0; i < 8; ++i) {
    const int cnt_i = cnts[i];
    const int cmi = min(cnt_i, kCap);
    const int cl = max(cmi - 1, 0);
    float4 acc = {0.f, 0.f, 0.f, 0.f};
    float rs = 0.f;

#pragma unroll
    for (int s = 0; s < 8; ++s) {
      const int sc = min(s, cl);
      const int eg = __shfl(b[i].x, sc, 64);
      const float qd = __int_as_float(__shfl(b[i].y, sc, 64));
      const float4 k4 = reinterpret_cast<const float4*>(key_embed)[(size_t)eg * 64 + lane];
      float d = k4.x * ck.x + k4.y * ck.y + k4.z * ck.z + k4.w * ck.w;
#pragma unroll
      for (int off = 1; off < 64; off <<= 1) d += __shfl_xor(d, off, 64);
      const float sv = d + qd;
      const float pl = (sv > 0.f) ? sv : kAlpha * sv;   // leaky_relu
      const float ev = (s < cmi) ? __expf(-pl) : 0.f;
      acc.x = fmaf(ev, k4.x, acc.x);
      acc.y = fmaf(ev, k4.y, acc.y);
      acc.z = fmaf(ev, k4.z, acc.z);
      acc.w = fmaf(ev, k4.w, acc.w);
      rs += ev;
    }

    for (int s = 8; s < cmi; ++s) {    // rare: deg 9..16 (wave-uniform loop)
      const int eg = __shfl(b[i].x, s, 64);
      const float qd = __int_as_float(__shfl(b[i].y, s, 64));
      const float4 k4 = reinterpret_cast<const float4*>(key_embed)[(size_t)eg * 64 + lane];
      float d = k4.x * ck.x + k4.y * ck.y + k4.z * ck.z + k4.w * ck.w;
#pragma unroll
      for (int off = 1; off < 64; off <<= 1) d += __shfl_xor(d, off, 64);
      const float sv = d + qd;
      const float pl = (sv > 0.f) ? sv : kAlpha * sv;
      const float ev = __expf(-pl);
      acc.x = fmaf(ev, k4.x, acc.x);
      acc.y = fmaf(ev, k4.y, acc.y);
      acc.z = fmaf(ev, k4.z, acc.z);
      acc.w = fmaf(ev, k4.w, acc.w);
      rs += ev;
    }

    if (cnt_i > kCap) {                // ultra-rare: scan overflow list
      const int q = qbase + i;
      const int n = min(*ovf_n, kOvfMax);
      for (int o = 0; o < n; ++o) {
        if (ovf_q[o] == q) {
          const float4 k4 = reinterpret_cast<const float4*>(key_embed)[(size_t)ovf_e[o] * 64 + lane];
          float d = k4.x * ck.x + k4.y * ck.y + k4.z * ck.z + k4.w * ck.w;
#pragma unroll
          for (int off = 1; off < 64; off <<= 1) d += __shfl_xor(d, off, 64);
          const float sv = d + ovf_qd[o];
          const float pl = (sv > 0.f) ? sv : kAlpha * sv;
          const float ev = __expf(-pl);
          acc.x = fmaf(ev, k4.x, acc.x);
          acc.y = fmaf(ev, k4.y, acc.y);
          acc.z = fmaf(ev, k4.z, acc.z);
          acc.w = fmaf(ev, k4.w, acc.w);
          rs += ev;
        }
      }
    }

    const float inv = 1.0f / ((rs == 0.f) ? kEps : rs);
    union { ushort4 u; __hip_bfloat16 h[4]; } pk;
    pk.h[0] = __float2bfloat16(acc.x * inv);
    pk.h[1] = __float2bfloat16(acc.y * inv);
    pk.h[2] = __float2bfloat16(acc.z * inv);
    pk.h[3] = __float2bfloat16(acc.w * inv);
    *reinterpret_cast<ushort4*>(&A_lds[wid * 8 + i][lane * 4]) = pk.u;
  }

  __syncthreads();

  // ---- phase 2: two M-tiles; each B fragment feeds both
  const int m = lane & 15;
  const int kb = (lane >> 4) * 8;
  f32x4 accA[4] = {};
  f32x4 accB[4] = {};

#pragma unroll
  for (int kt = 0; kt < kD; kt += 32) {
    const bf16x8 af0 = *reinterpret_cast<const bf16x8*>(&A_lds[m][kt + kb]);
    const bf16x8 af1 = *reinterpret_cast<const bf16x8*>(&A_lds[16 + m][kt + kb]);
#pragma unroll
    for (int nt = 0; nt < 4; ++nt) {
      const int ntg = wid * 4 + nt;
      const bf16x8 bf =
          *reinterpret_cast<const bf16x8*>(&B[(size_t)(ntg * 16 + m) * kD + kt + kb]);
      accA[nt] = __builtin_amdgcn_mfma_f32_16x16x32_bf16(af0, bf, accA[nt], 0, 0, 0);
      accB[nt] = __builtin_amdgcn_mfma_f32_16x16x32_bf16(af1, bf, accB[nt], 0, 0, 0);
    }
  }

#pragma unroll
  for (int nt = 0; nt < 4; ++nt) {
    const int ntg = wid * 4 + nt;
#pragma unroll
    for (int r = 0; r < 4; ++r) {
      const int rbase = blockIdx.x * 32 + (lane >> 4) * 4 + r;
      const float xa = accA[nt][r];
      out[(size_t)rbase * kDOUT + ntg * 16 + m] = (xa > 0.f) ? xa : expm1f(xa);
      const float xb = accB[nt][r];
      out[(size_t)(rbase + 16) * kDOUT + ntg * 16 + m] = (xb > 0.f) ? xb : expm1f(xb);
    }
  }
}

extern "C" void kernel_launch(void* const* d_in, const int* in_sizes, int n_in,
                              void* d_out, int out_size, void* d_ws, size_t ws_size,
                              hipStream_t stream) {
  // inputs: 0 key_list(int,E) [unused], 1 key_embed(f32,E*256), 2 query_list(int,E),
  //         3 query_embed(f32,E*256), 4 a(f32,256*512), 5 a_2(f32,256), 6 trans(f32,256*256)
  const float* key_embed = (const float*)d_in[1];
  const int* query_list = (const int*)d_in[2];
  const float* query_embed = (const float*)d_in[3];
  const float* a = (const float*)d_in[4];
  const float* a2 = (const float*)d_in[5];
  const float* trans = (const float*)d_in[6];
  float* out = (float*)d_out;

  // workspace (4B units):
  // c[512] | count[NQ] | bins[NQ*16 int2] | transb[256*256 us]
  // | ovf_n[4] | ovf_q[kOvfMax] | ovf_e[kOvfMax] | ovf_qd[kOvfMax]
  float* ws = (float*)d_ws;
  float* c = ws;
  int* count = (int*)(c + 512);
  int2* bins = (int2*)(count + kNQ);
  ushort* transb = (ushort*)(bins + (size_t)kNQ * kCap);
  int* ovf_n = (int*)(transb + (size_t)kDOUT * kD);
  int* ovf_q = ovf_n + 4;
  int* ovf_e = ovf_q + kOvfMax;
  float* ovf_qd = (float*)(ovf_e + kOvfMax);

  prep_kernel<<<130, 256, 0, stream>>>(a, a2, trans, (int4*)count, ovf_n, c, transb);
  qdot_bin_kernel<<<kE / 16, 256, 0, stream>>>(query_embed, query_list, c, count,
                                               bins, ovf_n, ovf_q, ovf_e, ovf_qd);
  gather_gemm_kernel<<<kNQ / 32, 256, 0, stream>>>(key_embed, c, bins, count, ovf_n,
                                                   ovf_q, ovf_e, ovf_qd, transb, out);
}

// Round 19
// 184.094 us; speedup vs baseline: 1.6282x; 1.0256x over previous
//
#include <hip/hip_runtime.h>
#include <hip/hip_bf16.h>
#include <math.h>

namespace {
constexpr int kD = 256;      // embed dim
constexpr int kDOUT = 256;   // out dim
constexpr int kNQ = 65536;   // num query nodes
constexpr int kE = 262144;   // edges
constexpr float kAlpha = 0.2f;
constexpr float kEps = 1e-12f;
constexpr int kCap = 16;     // slots per query
constexpr int kOvfMax = 4096;
}

typedef short bf16x8 __attribute__((ext_vector_type(8)));
typedef float f32x4 __attribute__((ext_vector_type(4)));
typedef unsigned short u16x8 __attribute__((ext_vector_type(8)));

// Fused prep: blocks 0..63 zero count (+ovf_n); 64..65 compute c; 66..129 cvt trans.
__global__ __launch_bounds__(256) void prep_kernel(
    const float* __restrict__ a,
    const float* __restrict__ a2,
    const float* __restrict__ trans,
    int4* __restrict__ count4,
    int* __restrict__ ovf_n,
    float* __restrict__ c,
    ushort* __restrict__ tb) {
  const int b = blockIdx.x;
  const int tid = threadIdx.x;
  if (b < 64) {
    count4[b * 256 + tid] = int4{0, 0, 0, 0};
    if (b == 0 && tid == 0) *ovf_n = 0;
  } else if (b < 66) {
    const int j = (b - 64) * 256 + tid;  // 0..511
    float s = 0.f;
#pragma unroll 8
    for (int k = 0; k < kDOUT; ++k) s = fmaf(a[k * (2 * kD) + j], a2[k], s);
    c[j] = s;
  } else {
    const int i = (b - 66) * 256 + tid;  // 0..16383, 4 elems each
    const float4 v = reinterpret_cast<const float4*>(trans)[i];
    union { ushort4 u; __hip_bfloat16 h[4]; } p;
    p.h[0] = __float2bfloat16(v.x);
    p.h[1] = __float2bfloat16(v.y);
    p.h[2] = __float2bfloat16(v.z);
    p.h[3] = __float2bfloat16(v.w);
    reinterpret_cast<ushort4*>(tb)[i] = p.u;
  }
}

// Sweep: reads ONLY query_embed. 4 edges per wave, 16 lanes per edge, each
// lane loads 4 float4 (quarter row). Group-lane-0 claims a capacity-bin slot
// and posts an 8B {edge, qd} store.
__global__ __launch_bounds__(256) void qdot_bin_kernel(
    const float* __restrict__ query_embed,
    const int* __restrict__ qlist,
    const float* __restrict__ c,          // cq at c[256..512)
    int* __restrict__ count,
    int2* __restrict__ bins,
    int* __restrict__ ovf_n,
    int* __restrict__ ovf_q,
    int* __restrict__ ovf_e,
    float* __restrict__ ovf_qd) {
  const int wid = threadIdx.x >> 6;
  const int lane = threadIdx.x & 63;
  const int g = lane >> 4;      // edge slot in wave
  const int l4 = lane & 15;     // lane in 16-group; floats [l4*16, +16)
  const int edge = blockIdx.x * 16 + wid * 4 + g;

  int q = 0;
  if (l4 == 0) q = qlist[edge];   // issued early, in flight under row loads

  const float4* qr = reinterpret_cast<const float4*>(query_embed) + (size_t)edge * 64 + l4 * 4;
  const float4 r0 = qr[0], r1 = qr[1], r2 = qr[2], r3 = qr[3];
  const float4 c0 = reinterpret_cast<const float4*>(c)[64 + l4 * 4 + 0];
  const float4 c1 = reinterpret_cast<const float4*>(c)[64 + l4 * 4 + 1];
  const float4 c2 = reinterpret_cast<const float4*>(c)[64 + l4 * 4 + 2];
  const float4 c3 = reinterpret_cast<const float4*>(c)[64 + l4 * 4 + 3];

  float s = r0.x * c0.x + r0.y * c0.y + r0.z * c0.z + r0.w * c0.w
          + r1.x * c1.x + r1.y * c1.y + r1.z * c1.z + r1.w * c1.w
          + r2.x * c2.x + r2.y * c2.y + r2.z * c2.z + r2.w * c2.w
          + r3.x * c3.x + r3.y * c3.y + r3.z * c3.z + r3.w * c3.w;
#pragma unroll
  for (int off = 1; off < 16; off <<= 1) s += __shfl_xor(s, off, 64);

  if (l4 == 0) {
    const int slot = atomicAdd(&count[q], 1);
    if (slot < kCap) {
      bins[q * kCap + slot] = make_int2(edge, __float_as_int(s));
    } else {
      const int o = atomicAdd(ovf_n, 1);
      if (o < kOvfMax) { ovf_q[o] = q; ovf_e[o] = edge; ovf_qd[o] = s; }
    }
  }
}

// Branchless static NS-slot accumulate for one query (whole-wave 1KB loads).
template <int NS>
static __device__ __forceinline__ void accum_slots(
    const float* __restrict__ key_embed, const float4 ck,
    const int bx, const int by, const int cmi, const int cl,
    float4& acc, float& rs) {
#pragma unroll
  for (int s = 0; s < NS; ++s) {
    const int sc = min(s, cl);
    const int eg = __shfl(bx, sc, 64);
    const float qd = __int_as_float(__shfl(by, sc, 64));
    const float4 k4 = reinterpret_cast<const float4*>(key_embed)[(size_t)eg * 64 +
                                                                 (threadIdx.x & 63)];
    float d = k4.x * ck.x + k4.y * ck.y + k4.z * ck.z + k4.w * ck.w;
#pragma unroll
    for (int off = 1; off < 64; off <<= 1) d += __shfl_xor(d, off, 64);
    const float sv = d + qd;
    const float pl = (sv > 0.f) ? sv : kAlpha * sv;   // leaky_relu
    const float ev = (s < cmi) ? __expf(-pl) : 0.f;
    acc.x = fmaf(ev, k4.x, acc.x);
    acc.y = fmaf(ev, k4.y, acc.y);
    acc.z = fmaf(ev, k4.z, acc.z);
    acc.w = fmaf(ev, k4.w, acc.w);
    rs += ev;
  }
}

// Fused gather + GEMM + elu. Block = 32 queries = two MFMA M-tiles.
// Phase 1: each WAVE owns 8 queries; counts + bin vectors preloaded. Per
// query, a degree-ADAPTIVE static loop (4 slots for deg<=4 [63%], 8 for
// deg<=8 [35%], dynamic beyond) of whole-wave 1KB row loads; 6-shfl reduce;
// ev = exp(-leaky(kd+qd)); f32 acc; normalized bf16 row -> padded LDS.
// Phase 2: wave w takes n-tiles 4w..4w+3; each B fragment feeds both M-tiles.
__global__ __launch_bounds__(256) void gather_gemm_kernel(
    const float* __restrict__ key_embed,
    const float* __restrict__ c,          // ck at c[0..256)
    const int2* __restrict__ bins,
    const int* __restrict__ count,
    const int* __restrict__ ovf_n,
    const int* __restrict__ ovf_q,
    const int* __restrict__ ovf_e,
    const float* __restrict__ ovf_qd,
    const ushort* __restrict__ B,         // trans bf16 (DOUT x D row-major)
    float* __restrict__ out) {
  __shared__ ushort A_lds[32][264];       // +8 pad
  const int wid = threadIdx.x >> 6;
  const int lane = threadIdx.x & 63;
  const int qbase = blockIdx.x * 32 + wid * 8;   // wave owns 8 queries

  // lane covers floats [lane*4, +4) of every row
  const float4 ck = reinterpret_cast<const float4*>(c)[lane];

  const int cnt_l = (lane < 8) ? count[qbase + lane] : 0;
  int2 b[8];
  int cnts[8];
#pragma unroll
  for (int i = 0; i < 8; ++i) {
    cnts[i] = __shfl(cnt_l, i, 64);
    const int cmi = min(cnts[i], kCap);
    b[i] = (lane < cmi) ? bins[(size_t)(qbase + i) * kCap + lane] : make_int2(0, 0);
  }

#pragma unroll
  for (int i = 0; i < 8; ++i) {
    const int cnt_i = cnts[i];
    const int cmi = min(cnt_i, kCap);
    const int cl = max(cmi - 1, 0);
    float4 acc = {0.f, 0.f, 0.f, 0.f};
    float rs = 0.f;

    if (cmi <= 4) {        // 63% of queries: 4 transactions
      accum_slots<4>(key_embed, ck, b[i].x, b[i].y, cmi, cl, acc, rs);
    } else {               // 35%: 8 transactions
      accum_slots<8>(key_embed, ck, b[i].x, b[i].y, cmi, cl, acc, rs);
      for (int s = 8; s < cmi; ++s) {  // rare: deg 9..16 (wave-uniform)
        const int eg = __shfl(b[i].x, s, 64);
        const float qd = __int_as_float(__shfl(b[i].y, s, 64));
        const float4 k4 = reinterpret_cast<const float4*>(key_embed)[(size_t)eg * 64 + lane];
        float d = k4.x * ck.x + k4.y * ck.y + k4.z * ck.z + k4.w * ck.w;
#pragma unroll
        for (int off = 1; off < 64; off <<= 1) d += __shfl_xor(d, off, 64);
        const float sv = d + qd;
        const float pl = (sv > 0.f) ? sv : kAlpha * sv;
        const float ev = __expf(-pl);
        acc.x = fmaf(ev, k4.x, acc.x);
        acc.y = fmaf(ev, k4.y, acc.y);
        acc.z = fmaf(ev, k4.z, acc.z);
        acc.w = fmaf(ev, k4.w, acc.w);
        rs += ev;
      }
    }

    if (cnt_i > kCap) {                // ultra-rare: scan overflow list
      const int q = qbase + i;
      const int n = min(*ovf_n, kOvfMax);
      for (int o = 0; o < n; ++o) {
        if (ovf_q[o] == q) {
          const float4 k4 = reinterpret_cast<const float4*>(key_embed)[(size_t)ovf_e[o] * 64 + lane];
          float d = k4.x * ck.x + k4.y * ck.y + k4.z * ck.z + k4.w * ck.w;
#pragma unroll
          for (int off = 1; off < 64; off <<= 1) d += __shfl_xor(d, off, 64);
          const float sv = d + ovf_qd[o];
          const float pl = (sv > 0.f) ? sv : kAlpha * sv;
          const float ev = __expf(-pl);
          acc.x = fmaf(ev, k4.x, acc.x);
          acc.y = fmaf(ev, k4.y, acc.y);
          acc.z = fmaf(ev, k4.z, acc.z);
          acc.w = fmaf(ev, k4.w, acc.w);
          rs += ev;
        }
      }
    }

    const float inv = 1.0f / ((rs == 0.f) ? kEps : rs);
    union { ushort4 u; __hip_bfloat16 h[4]; } pk;
    pk.h[0] = __float2bfloat16(acc.x * inv);
    pk.h[1] = __float2bfloat16(acc.y * inv);
    pk.h[2] = __float2bfloat16(acc.z * inv);
    pk.h[3] = __float2bfloat16(acc.w * inv);
    *reinterpret_cast<ushort4*>(&A_lds[wid * 8 + i][lane * 4]) = pk.u;
  }

  __syncthreads();

  // ---- phase 2: two M-tiles; each B fragment feeds both
  const int m = lane & 15;
  const int kb = (lane >> 4) * 8;
  f32x4 accA[4] = {};
  f32x4 accB[4] = {};

#pragma unroll
  for (int kt = 0; kt < kD; kt += 32) {
    const bf16x8 af0 = *reinterpret_cast<const bf16x8*>(&A_lds[m][kt + kb]);
    const bf16x8 af1 = *reinterpret_cast<const bf16x8*>(&A_lds[16 + m][kt + kb]);
#pragma unroll
    for (int nt = 0; nt < 4; ++nt) {
      const int ntg = wid * 4 + nt;
      const bf16x8 bf =
          *reinterpret_cast<const bf16x8*>(&B[(size_t)(ntg * 16 + m) * kD + kt + kb]);
      accA[nt] = __builtin_amdgcn_mfma_f32_16x16x32_bf16(af0, bf, accA[nt], 0, 0, 0);
      accB[nt] = __builtin_amdgcn_mfma_f32_16x16x32_bf16(af1, bf, accB[nt], 0, 0, 0);
    }
  }

#pragma unroll
  for (int nt = 0; nt < 4; ++nt) {
    const int ntg = wid * 4 + nt;
#pragma unroll
    for (int r = 0; r < 4; ++r) {
      const int rbase = blockIdx.x * 32 + (lane >> 4) * 4 + r;
      const float xa = accA[nt][r];
      out[(size_t)rbase * kDOUT + ntg * 16 + m] = (xa > 0.f) ? xa : expm1f(xa);
      const float xb = accB[nt][r];
      out[(size_t)(rbase + 16) * kDOUT + ntg * 16 + m] = (xb > 0.f) ? xb : expm1f(xb);
    }
  }
}

extern "C" void kernel_launch(void* const* d_in, const int* in_sizes, int n_in,
                              void* d_out, int out_size, void* d_ws, size_t ws_size,
                              hipStream_t stream) {
  // inputs: 0 key_list(int,E) [unused], 1 key_embed(f32,E*256), 2 query_list(int,E),
  //         3 query_embed(f32,E*256), 4 a(f32,256*512), 5 a_2(f32,256), 6 trans(f32,256*256)
  const float* key_embed = (const float*)d_in[1];
  const int* query_list = (const int*)d_in[2];
  const float* query_embed = (const float*)d_in[3];
  const float* a = (const float*)d_in[4];
  const float* a2 = (const float*)d_in[5];
  const float* trans = (const float*)d_in[6];
  float* out = (float*)d_out;

  // workspace (4B units):
  // c[512] | count[NQ] | bins[NQ*16 int2] | transb[256*256 us]
  // | ovf_n[4] | ovf_q[kOvfMax] | ovf_e[kOvfMax] | ovf_qd[kOvfMax]
  float* ws = (float*)d_ws;
  float* c = ws;
  int* count = (int*)(c + 512);
  int2* bins = (int2*)(count + kNQ);
  ushort* transb = (ushort*)(bins + (size_t)kNQ * kCap);
  int* ovf_n = (int*)(transb + (size_t)kDOUT * kD);
  int* ovf_q = ovf_n + 4;
  int* ovf_e = ovf_q + kOvfMax;
  float* ovf_qd = (float*)(ovf_e + kOvfMax);

  prep_kernel<<<130, 256, 0, stream>>>(a, a2, trans, (int4*)count, ovf_n, c, transb);
  qdot_bin_kernel<<<kE / 16, 256, 0, stream>>>(query_embed, query_list, c, count,
                                               bins, ovf_n, ovf_q, ovf_e, ovf_qd);
  gather_gemm_kernel<<<kNQ / 32, 256, 0, stream>>>(key_embed, c, bins, count, ovf_n,
                                                   ovf_q, ovf_e, ovf_qd, transb, out);
}